// Round 1
// baseline (674.091 us; speedup 1.0000x reference)
//
#include <hip/hip_runtime.h>
#include <math.h>
#include <float.h>

#define IN_DIM 256
#define OUT_DIM 512
#define MEM_LEN 131072
#define K_TOP 16

// Kernel 1: xn = (data-mean)/std (std==0 -> 0); enc = tanh(xn @ W + b)
// One block, 512 threads. W is [IN_DIM, OUT_DIM] row-major so thread j reading
// W[i*OUT_DIM + j] is coalesced across j.
__global__ void enc_kernel(const float* __restrict__ data,
                           const float* __restrict__ mean,
                           const float* __restrict__ stdv,
                           const float* __restrict__ W,
                           const float* __restrict__ b,
                           float* __restrict__ enc) {
    __shared__ float xn[IN_DIM];
    int t = threadIdx.x;
    if (t < IN_DIM) {
        float s = stdv[t];
        xn[t] = (s == 0.0f) ? 0.0f : (data[t] - mean[t]) / s;
    }
    __syncthreads();
    float acc = b[t];
#pragma unroll 8
    for (int i = 0; i < IN_DIM; ++i)
        acc = fmaf(xn[i], W[i * OUT_DIM + t], acc);
    enc[t] = tanhf(acc);
}

// Kernel 2: dist[row] = sum_j |memory[row][j] - enc[j]|
// One wave (64 lanes) per row, grid-stride over rows. Each lane reads two
// float4 (cols lane*4 and 256+lane*4) -> the wave covers the full 2KB row
// with perfectly coalesced 16B/lane loads.
__global__ void dist_kernel(const float* __restrict__ memory,
                            const float* __restrict__ enc,
                            float* __restrict__ dist) {
    const int lane = threadIdx.x & 63;
    const int wavesPerBlock = blockDim.x >> 6;
    const int wave = blockIdx.x * wavesPerBlock + (threadIdx.x >> 6);
    const int nwaves = gridDim.x * wavesPerBlock;

    const float4 e0 = *(const float4*)(enc + lane * 4);
    const float4 e1 = *(const float4*)(enc + 256 + lane * 4);

    for (int row = wave; row < MEM_LEN; row += nwaves) {
        const float* mrow = memory + (size_t)row * OUT_DIM;
        const float4 m0 = *(const float4*)(mrow + lane * 4);
        const float4 m1 = *(const float4*)(mrow + 256 + lane * 4);
        float s = fabsf(m0.x - e0.x) + fabsf(m0.y - e0.y)
                + fabsf(m0.z - e0.z) + fabsf(m0.w - e0.w)
                + fabsf(m1.x - e1.x) + fabsf(m1.y - e1.y)
                + fabsf(m1.z - e1.z) + fabsf(m1.w - e1.w);
#pragma unroll
        for (int off = 32; off > 0; off >>= 1)
            s += __shfl_down(s, off, 64);
        if (lane == 0) dist[row] = s;
    }
}

// Kernel 3: top-16 smallest of dist[131072] (ascending), weighted by exp_w.
// One block, 256 threads. Per-thread top-16 kept in LDS (dynamic index),
// then 16 rounds of block min-extraction.
__global__ void topk_loss_kernel(const float* __restrict__ dist,
                                 const float* __restrict__ exp_w,
                                 float* __restrict__ out) {
    __shared__ float cands[256][K_TOP + 1];  // +1 pad vs bank aliasing
    __shared__ float redv[256];
    __shared__ int flag;
    const int t = threadIdx.x;

    for (int j = 0; j < K_TOP; ++j) cands[t][j] = FLT_MAX;
    float cmax = FLT_MAX;
    int cmaxi = 0;

    for (int i = t; i < MEM_LEN; i += 256) {
        float d = dist[i];
        if (d < cmax) {
            cands[t][cmaxi] = d;
            cmax = cands[t][0]; cmaxi = 0;
            for (int j = 1; j < K_TOP; ++j)
                if (cands[t][j] > cmax) { cmax = cands[t][j]; cmaxi = j; }
        }
    }
    __syncthreads();

    float num = 0.0f;
    for (int k = 0; k < K_TOP; ++k) {
        float lmin = cands[t][0];
        for (int j = 1; j < K_TOP; ++j) lmin = fminf(lmin, cands[t][j]);
        redv[t] = lmin;
        if (t == 0) flag = 0;
        __syncthreads();
        for (int s = 128; s > 0; s >>= 1) {
            if (t < s) redv[t] = fminf(redv[t], redv[t + s]);
            __syncthreads();
        }
        float gmin = redv[0];
        // exactly one thread removes one instance of gmin
        int ji = -1;
        for (int j = 0; j < K_TOP; ++j)
            if (cands[t][j] == gmin) { ji = j; break; }
        if (ji >= 0 && atomicExch(&flag, 1) == 0) cands[t][ji] = FLT_MAX;
        __syncthreads();
        if (t == 0) num += gmin * exp_w[k];
    }

    if (t == 0) {
        float den = 0.0f;
        for (int k = 0; k < K_TOP; ++k) den += exp_w[k];
        out[0] = num / den;
    }
}

extern "C" void kernel_launch(void* const* d_in, const int* in_sizes, int n_in,
                              void* d_out, int out_size, void* d_ws, size_t ws_size,
                              hipStream_t stream) {
    const float* data   = (const float*)d_in[0];
    const float* mean   = (const float*)d_in[1];
    const float* stdv   = (const float*)d_in[2];
    const float* memory = (const float*)d_in[3];
    const float* W      = (const float*)d_in[4];
    const float* b      = (const float*)d_in[5];
    const float* exp_w  = (const float*)d_in[6];
    float* out = (float*)d_out;

    float* enc  = (float*)d_ws;          // 512 floats
    float* dist = enc + OUT_DIM;         // 131072 floats (total ~526 KB)

    enc_kernel<<<1, OUT_DIM, 0, stream>>>(data, mean, stdv, W, b, enc);
    dist_kernel<<<2048, 256, 0, stream>>>(memory, enc, dist);
    topk_loss_kernel<<<1, 256, 0, stream>>>(dist, exp_w, out);
}

// Round 2
// 422.312 us; speedup vs baseline: 1.5962x; 1.5962x over previous
//
#include <hip/hip_runtime.h>
#include <math.h>
#include <float.h>

#define IN_DIM 256
#define OUT_DIM 512
#define MEM_LEN 131072
#define K_TOP 16

#define BLOCKS_A 512
#define ROWS_PER_BLOCK (MEM_LEN / BLOCKS_A)   // 256
#define CAND_N (BLOCKS_A * K_TOP)             // 8192

// ---------------------------------------------------------------------------
// Kernel 1: xn = (data-mean)/std (std==0 -> 0); encAcc = b (bias init).
// One block, 512 threads.
__global__ void init_kernel(const float* __restrict__ data,
                            const float* __restrict__ mean,
                            const float* __restrict__ stdv,
                            const float* __restrict__ b,
                            float* __restrict__ xn,
                            float* __restrict__ encAcc) {
    int t = threadIdx.x;
    if (t < IN_DIM) {
        float s = stdv[t];
        xn[t] = (s == 0.0f) ? 0.0f : (data[t] - mean[t]) / s;
    }
    encAcc[t] = b[t];
}

// ---------------------------------------------------------------------------
// Kernel 2: split-K GEMV partial: encAcc[c] += sum_{i in block's K-slice} xn[i]*W[i][c]
// 16 blocks x 512 threads; block g covers i in [g*16, g*16+16).
// W reads are coalesced across threads (thread t = column t).
__global__ void gemv_partial_kernel(const float* __restrict__ xn,
                                    const float* __restrict__ W,
                                    float* __restrict__ encAcc) {
    const int t = threadIdx.x;       // column
    const int g = blockIdx.x;        // K-slice
    float acc = 0.0f;
#pragma unroll
    for (int j = 0; j < 16; ++j) {
        int i = g * 16 + j;
        acc = fmaf(xn[i], W[i * OUT_DIM + t], acc);
    }
    atomicAdd(&encAcc[t], acc);
}

// ---------------------------------------------------------------------------
// Kernel 3: dist + per-block top-16.
// 512 blocks x 1024 threads (16 waves). Block b handles rows [b*256, b*256+256).
// In iteration `it`, wave w reads row base + it*16 + w  -> 16 consecutive 2KB
// rows per iteration, perfectly coalesced float4 loads (16B/lane).
// enc = tanh(encAcc) applied on load (8 tanhf per wave, once).
// Block-local dists go to LDS; wave 0 extracts the block's 16 smallest via
// shuffle min-reduction (no extra barriers) and writes them to cand[].
__global__ __launch_bounds__(1024)
void dist_topk_kernel(const float* __restrict__ memory,
                      const float* __restrict__ encAcc,
                      float* __restrict__ cand) {
    __shared__ float bd[ROWS_PER_BLOCK];
    const int t = threadIdx.x;
    const int lane = t & 63;
    const int w = t >> 6;                       // wave id 0..15
    const int base = blockIdx.x * ROWS_PER_BLOCK;

    float4 ea = *(const float4*)(encAcc + lane * 4);
    float4 eb = *(const float4*)(encAcc + 256 + lane * 4);
    float4 e0, e1;
    e0.x = tanhf(ea.x); e0.y = tanhf(ea.y); e0.z = tanhf(ea.z); e0.w = tanhf(ea.w);
    e1.x = tanhf(eb.x); e1.y = tanhf(eb.y); e1.z = tanhf(eb.z); e1.w = tanhf(eb.w);

    for (int it = 0; it < ROWS_PER_BLOCK / 16; ++it) {
        const int slot = it * 16 + w;
        const float* mrow = memory + (size_t)(base + slot) * OUT_DIM;
        const float4 m0 = *(const float4*)(mrow + lane * 4);
        const float4 m1 = *(const float4*)(mrow + 256 + lane * 4);
        float s = fabsf(m0.x - e0.x) + fabsf(m0.y - e0.y)
                + fabsf(m0.z - e0.z) + fabsf(m0.w - e0.w)
                + fabsf(m1.x - e1.x) + fabsf(m1.y - e1.y)
                + fabsf(m1.z - e1.z) + fabsf(m1.w - e1.w);
#pragma unroll
        for (int off = 32; off > 0; off >>= 1)
            s += __shfl_down(s, off, 64);
        if (lane == 0) bd[slot] = s;
    }
    __syncthreads();

    // Wave 0: extract 16 smallest of the 256 block dists.
    if (t < 64) {
        float v0 = bd[t * 4 + 0];
        float v1 = bd[t * 4 + 1];
        float v2 = bd[t * 4 + 2];
        float v3 = bd[t * 4 + 3];
#pragma unroll 1
        for (int k = 0; k < K_TOP; ++k) {
            float lmin = fminf(fminf(v0, v1), fminf(v2, v3));
            float m = lmin;
#pragma unroll
            for (int off = 32; off > 0; off >>= 1)
                m = fminf(m, __shfl_xor(m, off, 64));
            unsigned long long mask = __ballot(lmin == m);
            int src = __ffsll(mask) - 1;
            if (t == src) {
                if      (v0 == m) v0 = FLT_MAX;
                else if (v1 == m) v1 = FLT_MAX;
                else if (v2 == m) v2 = FLT_MAX;
                else              v3 = FLT_MAX;
            }
            if (t == 0) cand[blockIdx.x * K_TOP + k] = m;
        }
    }
}

// ---------------------------------------------------------------------------
// Kernel 4: global top-16 over 8192 candidates (L2-resident), weighted sum.
// One block, 256 threads; per-thread top-16 in LDS, then 16 extraction rounds.
__global__ void final_topk_kernel(const float* __restrict__ cand,
                                  const float* __restrict__ exp_w,
                                  float* __restrict__ out) {
    __shared__ float cands[256][K_TOP + 1];
    __shared__ float redv[256];
    __shared__ int flag;
    const int t = threadIdx.x;

    for (int j = 0; j < K_TOP; ++j) cands[t][j] = FLT_MAX;
    float cmax = FLT_MAX;
    int cmaxi = 0;

    for (int i = t; i < CAND_N; i += 256) {
        float d = cand[i];
        if (d < cmax) {
            cands[t][cmaxi] = d;
            cmax = cands[t][0]; cmaxi = 0;
            for (int j = 1; j < K_TOP; ++j)
                if (cands[t][j] > cmax) { cmax = cands[t][j]; cmaxi = j; }
        }
    }
    __syncthreads();

    float num = 0.0f;
    for (int k = 0; k < K_TOP; ++k) {
        float lmin = cands[t][0];
        for (int j = 1; j < K_TOP; ++j) lmin = fminf(lmin, cands[t][j]);
        redv[t] = lmin;
        if (t == 0) flag = 0;
        __syncthreads();
        for (int s = 128; s > 0; s >>= 1) {
            if (t < s) redv[t] = fminf(redv[t], redv[t + s]);
            __syncthreads();
        }
        float gmin = redv[0];
        int ji = -1;
        for (int j = 0; j < K_TOP; ++j)
            if (cands[t][j] == gmin) { ji = j; break; }
        if (ji >= 0 && atomicExch(&flag, 1) == 0) cands[t][ji] = FLT_MAX;
        __syncthreads();
        if (t == 0) num += gmin * exp_w[k];
    }

    if (t == 0) {
        float den = 0.0f;
        for (int k = 0; k < K_TOP; ++k) den += exp_w[k];
        out[0] = num / den;
    }
}

extern "C" void kernel_launch(void* const* d_in, const int* in_sizes, int n_in,
                              void* d_out, int out_size, void* d_ws, size_t ws_size,
                              hipStream_t stream) {
    const float* data   = (const float*)d_in[0];
    const float* mean   = (const float*)d_in[1];
    const float* stdv   = (const float*)d_in[2];
    const float* memory = (const float*)d_in[3];
    const float* W      = (const float*)d_in[4];
    const float* b      = (const float*)d_in[5];
    const float* exp_w  = (const float*)d_in[6];
    float* out = (float*)d_out;

    float* xn     = (float*)d_ws;            // 256 floats
    float* encAcc = xn + IN_DIM;             // 512 floats
    float* cand   = encAcc + OUT_DIM;        // 8192 floats

    init_kernel<<<1, OUT_DIM, 0, stream>>>(data, mean, stdv, b, xn, encAcc);
    gemv_partial_kernel<<<IN_DIM / 16, OUT_DIM, 0, stream>>>(xn, W, encAcc);
    dist_topk_kernel<<<BLOCKS_A, 1024, 0, stream>>>(memory, encAcc, cand);
    final_topk_kernel<<<1, 256, 0, stream>>>(cand, exp_w, out);
}

// Round 3
// 420.980 us; speedup vs baseline: 1.6012x; 1.0032x over previous
//
#include <hip/hip_runtime.h>
#include <math.h>
#include <float.h>

#define IN_DIM 256
#define OUT_DIM 512
#define MEM_LEN 131072
#define K_TOP 16

#define DIST_BLOCKS 2048
#define DIST_THREADS 256            // 4 waves/block -> 8192 waves, 16 rows/wave
#define S1_BLOCKS 16
#define S1_SPAN (MEM_LEN / S1_BLOCKS)   // 8192 dists per stage-1 block
#define CAND_N (S1_BLOCKS * K_TOP)      // 256 candidates

// ---------------------------------------------------------------------------
// Kernel 1: encAcc[t] = b[t]  (bias init; gemv blocks atomicAdd partials on top)
__global__ void init_kernel(const float* __restrict__ b,
                            float* __restrict__ encAcc) {
    encAcc[threadIdx.x] = b[threadIdx.x];
}

// ---------------------------------------------------------------------------
// Kernel 2: split-K GEMV, xn computed in-block (no xn round-trip).
// 32 blocks x 512 threads; block g covers k in [g*8, g*8+8).
__global__ void gemv_kernel(const float* __restrict__ data,
                            const float* __restrict__ mean,
                            const float* __restrict__ stdv,
                            const float* __restrict__ W,
                            float* __restrict__ encAcc) {
    __shared__ float xn_s[8];
    const int t = threadIdx.x;        // column
    const int g = blockIdx.x;         // K-slice
    if (t < 8) {
        int i = g * 8 + t;
        float s = stdv[i];
        xn_s[t] = (s == 0.0f) ? 0.0f : (data[i] - mean[i]) / s;
    }
    __syncthreads();
    float acc = 0.0f;
#pragma unroll
    for (int j = 0; j < 8; ++j)
        acc = fmaf(xn_s[j], W[(g * 8 + j) * OUT_DIM + t], acc);
    atomicAdd(&encAcc[t], acc);
}

// ---------------------------------------------------------------------------
// Kernel 3: pure streaming dist. One wave per 16 consecutive rows; lane reads
// two float4 per row (16B/lane, wave covers the full 2KB row). No LDS, no
// barriers, no tail — maximize HBM streaming.
__global__ __launch_bounds__(DIST_THREADS)
void dist_kernel(const float* __restrict__ memory,
                 const float* __restrict__ encAcc,
                 float* __restrict__ dist) {
    const int lane = threadIdx.x & 63;
    const int wave = blockIdx.x * (DIST_THREADS / 64) + (threadIdx.x >> 6);

    float4 ea = *(const float4*)(encAcc + lane * 4);
    float4 eb = *(const float4*)(encAcc + 256 + lane * 4);
    float4 e0, e1;
    e0.x = tanhf(ea.x); e0.y = tanhf(ea.y); e0.z = tanhf(ea.z); e0.w = tanhf(ea.w);
    e1.x = tanhf(eb.x); e1.y = tanhf(eb.y); e1.z = tanhf(eb.z); e1.w = tanhf(eb.w);

    const int row0 = wave * 16;
    const float* mrow = memory + (size_t)row0 * OUT_DIM;
#pragma unroll 2
    for (int r = 0; r < 16; ++r) {
        const float4 m0 = *(const float4*)(mrow + lane * 4);
        const float4 m1 = *(const float4*)(mrow + 256 + lane * 4);
        float s = fabsf(m0.x - e0.x) + fabsf(m0.y - e0.y)
                + fabsf(m0.z - e0.z) + fabsf(m0.w - e0.w)
                + fabsf(m1.x - e1.x) + fabsf(m1.y - e1.y)
                + fabsf(m1.z - e1.z) + fabsf(m1.w - e1.w);
#pragma unroll
        for (int off = 32; off > 0; off >>= 1)
            s += __shfl_down(s, off, 64);
        if (lane == 0) dist[row0 + r] = s;
        mrow += OUT_DIM;
    }
}

// ---------------------------------------------------------------------------
// Kernel 4: stage-1 top-16. 16 blocks x 256 threads; block b scans
// dist[b*8192 .. +8192) (32 values/thread), per-thread top-16 in LDS, then
// 16 block-wide min-extraction rounds -> cand[b*16+k] ascending.
__global__ void topk_stage1(const float* __restrict__ dist,
                            float* __restrict__ cand) {
    __shared__ float cands[256][K_TOP + 1];
    __shared__ float redv[256];
    __shared__ int flag;
    const int t = threadIdx.x;
    const int base = blockIdx.x * S1_SPAN;

    for (int j = 0; j < K_TOP; ++j) cands[t][j] = FLT_MAX;
    float cmax = FLT_MAX;
    int cmaxi = 0;

    for (int i = t; i < S1_SPAN; i += 256) {
        float d = dist[base + i];
        if (d < cmax) {
            cands[t][cmaxi] = d;
            cmax = cands[t][0]; cmaxi = 0;
            for (int j = 1; j < K_TOP; ++j)
                if (cands[t][j] > cmax) { cmax = cands[t][j]; cmaxi = j; }
        }
    }
    __syncthreads();

    for (int k = 0; k < K_TOP; ++k) {
        float lmin = cands[t][0];
        for (int j = 1; j < K_TOP; ++j) lmin = fminf(lmin, cands[t][j]);
        redv[t] = lmin;
        if (t == 0) flag = 0;
        __syncthreads();
        for (int s = 128; s > 0; s >>= 1) {
            if (t < s) redv[t] = fminf(redv[t], redv[t + s]);
            __syncthreads();
        }
        float gmin = redv[0];
        int ji = -1;
        for (int j = 0; j < K_TOP; ++j)
            if (cands[t][j] == gmin) { ji = j; break; }
        if (ji >= 0 && atomicExch(&flag, 1) == 0) cands[t][ji] = FLT_MAX;
        __syncthreads();
        if (t == 0) cand[blockIdx.x * K_TOP + k] = gmin;
    }
}

// ---------------------------------------------------------------------------
// Kernel 5: stage-2 — exact top-16 of 256 candidates via one wave, weighted sum.
__global__ void topk_stage2(const float* __restrict__ cand,
                            const float* __restrict__ exp_w,
                            float* __restrict__ out) {
    const int t = threadIdx.x;   // 64 threads
    float v0 = cand[t * 4 + 0];
    float v1 = cand[t * 4 + 1];
    float v2 = cand[t * 4 + 2];
    float v3 = cand[t * 4 + 3];
    float num = 0.0f;
#pragma unroll 1
    for (int k = 0; k < K_TOP; ++k) {
        float lmin = fminf(fminf(v0, v1), fminf(v2, v3));
        float m = lmin;
#pragma unroll
        for (int off = 32; off > 0; off >>= 1)
            m = fminf(m, __shfl_xor(m, off, 64));
        unsigned long long mask = __ballot(lmin == m);
        int src = __ffsll(mask) - 1;
        if (t == src) {
            if      (v0 == m) v0 = FLT_MAX;
            else if (v1 == m) v1 = FLT_MAX;
            else if (v2 == m) v2 = FLT_MAX;
            else              v3 = FLT_MAX;
        }
        if (t == 0) num += m * exp_w[k];
    }
    if (t == 0) {
        float den = 0.0f;
        for (int k = 0; k < K_TOP; ++k) den += exp_w[k];
        out[0] = num / den;
    }
}

extern "C" void kernel_launch(void* const* d_in, const int* in_sizes, int n_in,
                              void* d_out, int out_size, void* d_ws, size_t ws_size,
                              hipStream_t stream) {
    const float* data   = (const float*)d_in[0];
    const float* mean   = (const float*)d_in[1];
    const float* stdv   = (const float*)d_in[2];
    const float* memory = (const float*)d_in[3];
    const float* W      = (const float*)d_in[4];
    const float* b      = (const float*)d_in[5];
    const float* exp_w  = (const float*)d_in[6];
    float* out = (float*)d_out;

    float* encAcc = (float*)d_ws;            // 512 floats
    float* dist   = encAcc + OUT_DIM;        // 131072 floats
    float* cand   = dist + MEM_LEN;          // 256 floats

    init_kernel<<<1, OUT_DIM, 0, stream>>>(b, encAcc);
    gemv_kernel<<<32, OUT_DIM, 0, stream>>>(data, mean, stdv, W, encAcc);
    dist_kernel<<<DIST_BLOCKS, DIST_THREADS, 0, stream>>>(memory, encAcc, dist);
    topk_stage1<<<S1_BLOCKS, 256, 0, stream>>>(dist, cand);
    topk_stage2<<<1, 64, 0, stream>>>(cand, exp_w, out);
}